// Round 19
// baseline (47.625 us; speedup 1.0000x reference)
//
#include <hip/hip_runtime.h>

// DynamicMaskHead, barrier-free vertical-band rolling kernel (3rd rolling
// attempt; prior flaws fixed: R12 = per-px LDS weight reads, R14 = dynamic
// loop forcing per-iteration weight reloads). Thread owns ONE column x a
// 4-row band: computes 6 logit rows (+-1 halo) in a FULLY UNROLLED straight-
// line body (scalar uniform weight loads, hoistable; no loop -> no spill),
// exchanges x-neighbors via 12 wave shuffles, then emits its 16-row x 4-col
// output block. ZERO LDS, ZERO barriers: stores issue early and spread over
// the kernel so the 95.5MB drain (~15us floor) overlaps the ~11us compute --
// phase-structured variants serialized these (R13 = 30.9us plateau).
// Sigmoid fold kept (R15-proven): tile value = -log2e*logit, interp commutes,
// sigmoid = rcp(1+2^z). Mish in natural domain (R13-proven formula).
// Wave covers 64 cols, emits 62 (lanes 0,63 halo); 3 waves cover W=152.
// Shapes fixed by harness: N=2, Cin=8, H=100, W=152, n_inst=100, stride=8.

#define CIN 8
#define HH 100
#define WW 152
#define HWSZ (HH * WW)
#define NI 100
#define OH (HH * 4)
#define OW (WW * 4)
#define TRB 4                              // owned input rows per block band
#define WROWS (TRB + 2)                    // computed logit rows (halo)
#define BLOCK 192                          // 3 waves
#define NLOG2E (-1.44269504f)

__device__ __forceinline__ float fast_rcp(float x) {
    return __builtin_amdgcn_rcpf(x);       // v_rcp_f32, ~1 ulp
}

__device__ __forceinline__ float fast_mish(float x) {
    // mish(x) = x*n/(n+2), n=e(e+2), e=exp(x); clamp only exp arg (x>20 ->
    // factor==1 in fp32) -> branchless, exact. (R13-proven)
    float e = __expf(fminf(x, 20.f));
    float n = e * (e + 2.f);
    return x * n * fast_rcp(n + 2.f);
}

// folded sigmoid: z = -log2e*logit -> sigma = 1/(1+2^z)  (R15-proven)
__device__ __forceinline__ float fold_sigmoid(float z) {
    return fast_rcp(1.f + exp2f(z));
}

__global__ void __launch_bounds__(BLOCK)
fused_mask_head_kernel(const float* __restrict__ mask_feats,
                       const float* __restrict__ params,
                       const float* __restrict__ inst_locs,
                       const int* __restrict__ im_inds,
                       const int* __restrict__ fpn_levels,
                       const int* __restrict__ stride_ptr,
                       float* __restrict__ out) {
    const int inst = blockIdx.y;
    const int r0 = blockIdx.x * TRB;       // first owned input row
    const int t = threadIdx.x;
    const int wave = t >> 6;
    const int lane = t & 63;
    const int c = wave * 62 + lane - 1;    // center column (halo lanes 0,63)
    const int colc = min(max(c, 0), WW - 1);
    const bool emit_ok = (lane >= 1) && (lane <= 62) && (c < WW);  // c>=0 given lane>=1

    // block-uniform weight pointer -> s_load/SGPR operands (R13-proven)
    const float* __restrict__ P = params + inst * 169;

    const int stride = stride_ptr[0];
    const float half = (float)(stride / 2);
    const float soi_tab[5] = {64.f, 128.f, 256.f, 512.f, 1024.f};
    const float inv_soi = 1.f / soi_tab[fpn_levels[inst]];
    const float lx = inst_locs[inst * 2 + 0];
    const float ly = inst_locs[inst * 2 + 1];
    const float xrel = (lx - (float)(colc * stride) - half) * inv_soi;
    const float* fcol = mask_feats + (size_t)im_inds[inst] * CIN * HWSZ + colc;
    float* const obase = out + (size_t)inst * (OH * OW);

    const float b3f = NLOG2E * P[168];     // folded b3 (uniform)

    // ---- 6-row straight-line MLP: folded logits Lw[0..5] for rows r0-1..r0+4 ----
    float Lw[WROWS];
#pragma unroll
    for (int i = 0; i < WROWS; ++i) {
        const int rr = min(max(r0 + i - 1, 0), HH - 1);
        const float relY = (ly - (float)(rr * stride) - half) * inv_soi;

        float fv[CIN];
        const float* fr = fcol + rr * WW;
#pragma unroll
        for (int ch = 0; ch < CIN; ++ch) fv[ch] = fr[(size_t)ch * HWSZ];

        // layer 1: 10 -> 8, mish
        float h1[8];
#pragma unroll
        for (int o = 0; o < 8; ++o) {
            float acc = fmaf(P[o * 10 + 0], xrel, fmaf(P[o * 10 + 1], relY, P[152 + o]));
#pragma unroll
            for (int ch = 0; ch < CIN; ++ch) acc = fmaf(P[o * 10 + 2 + ch], fv[ch], acc);
            h1[o] = fast_mish(acc);
        }
        // layers 2+3 fused, sigmoid-fold on w3/b3
        float L = b3f;
#pragma unroll
        for (int o = 0; o < 8; ++o) {
            float acc = P[160 + o];
#pragma unroll
            for (int ii = 0; ii < 8; ++ii) acc = fmaf(P[80 + o * 8 + ii], h1[ii], acc);
            L = fmaf(NLOG2E * P[144 + o], fast_mish(acc), L);
        }
        Lw[i] = L;
    }

    // ---- x-neighbors via shuffles (all lanes participate) ----
    float Ll[WROWS], Lr[WROWS];
#pragma unroll
    for (int i = 0; i < WROWS; ++i) {
        Ll[i] = __shfl_up(Lw[i], 1);
        Lr[i] = __shfl_down(Lw[i], 1);
    }

    // ---- emit: 4 owned input rows -> 16 output rows x 4 cols ----
    if (emit_ok) {
#pragma unroll
        for (int k = 0; k < TRB; ++k) {
            // window rows k (prev), k+1 (cur), k+2 (next)
            const float pl = Ll[k],     pm = Lw[k],     pr = Lr[k];
            const float cl = Ll[k + 1], cm = Lw[k + 1], cr = Lr[k + 1];
            const float nl = Ll[k + 2], nm = Lw[k + 2], nr = Lr[k + 2];

            // horizontal interp: x-samples k0=.5(L+C) k1=.25L+.75C k2=C k3=.75C+.25R
            float hp[4], hc[4], hn[4];
            hp[0] = 0.5f * (pl + pm); hp[1] = fmaf(0.25f, pl, 0.75f * pm); hp[2] = pm; hp[3] = fmaf(0.25f, pr, 0.75f * pm);
            hc[0] = 0.5f * (cl + cm); hc[1] = fmaf(0.25f, cl, 0.75f * cm); hc[2] = cm; hc[3] = fmaf(0.25f, cr, 0.75f * cm);
            hn[0] = 0.5f * (nl + nm); hn[1] = fmaf(0.25f, nl, 0.75f * nm); hn[2] = nm; hn[3] = fmaf(0.25f, nr, 0.75f * nm);

            float* O = obase + (size_t)(4 * (r0 + k)) * OW + 4 * c;
            float4 row;
            // out row 0: .5 prev + .5 cur
            row.x = fold_sigmoid(0.5f * (hp[0] + hc[0]));
            row.y = fold_sigmoid(0.5f * (hp[1] + hc[1]));
            row.z = fold_sigmoid(0.5f * (hp[2] + hc[2]));
            row.w = fold_sigmoid(0.5f * (hp[3] + hc[3]));
            *reinterpret_cast<float4*>(O) = row;
            // out row 1: .25 prev + .75 cur
            row.x = fold_sigmoid(fmaf(0.25f, hp[0], 0.75f * hc[0]));
            row.y = fold_sigmoid(fmaf(0.25f, hp[1], 0.75f * hc[1]));
            row.z = fold_sigmoid(fmaf(0.25f, hp[2], 0.75f * hc[2]));
            row.w = fold_sigmoid(fmaf(0.25f, hp[3], 0.75f * hc[3]));
            *reinterpret_cast<float4*>(O + OW) = row;
            // out row 2: cur
            row.x = fold_sigmoid(hc[0]);
            row.y = fold_sigmoid(hc[1]);
            row.z = fold_sigmoid(hc[2]);
            row.w = fold_sigmoid(hc[3]);
            *reinterpret_cast<float4*>(O + 2 * OW) = row;
            // out row 3: .75 cur + .25 next
            row.x = fold_sigmoid(fmaf(0.25f, hn[0], 0.75f * hc[0]));
            row.y = fold_sigmoid(fmaf(0.25f, hn[1], 0.75f * hc[1]));
            row.z = fold_sigmoid(fmaf(0.25f, hn[2], 0.75f * hc[2]));
            row.w = fold_sigmoid(fmaf(0.25f, hn[3], 0.75f * hc[3]));
            *reinterpret_cast<float4*>(O + 3 * OW) = row;
        }
    }
}

extern "C" void kernel_launch(void* const* d_in, const int* in_sizes, int n_in,
                              void* d_out, int out_size, void* d_ws, size_t ws_size,
                              hipStream_t stream) {
    const float* mask_feats = (const float*)d_in[0];
    const float* params     = (const float*)d_in[1];
    const float* inst_locs  = (const float*)d_in[2];
    const int*   im_inds    = (const int*)d_in[3];
    const int*   fpn_levels = (const int*)d_in[4];
    const int*   stride_ptr = (const int*)d_in[5];
    float* out = (float*)d_out;

    dim3 block(BLOCK);
    dim3 grid(HH / TRB, NI);               // 25 x 100 = 2500 blocks
    fused_mask_head_kernel<<<grid, block, 0, stream>>>(
        mask_feats, params, inst_locs, im_inds, fpn_levels, stride_ptr, out);
}

// Round 20
// 39.908 us; speedup vs baseline: 1.1934x; 1.1934x over previous
//
#include <hip/hip_runtime.h>

// DynamicMaskHead, TWO-kernel split with both proven-fast components:
//  K1: R13's quad-MLP (scalar uniform weights -> s_load/SGPR; one 4-px quad
//      per thread, straight-line; NO halo, NO LDS, NO barrier) -> folded
//      logits (-log2e * logit, R15 algebra) to d_ws.  ~6-8us.
//  K2: R2/R6's streaming upsample: one thread per input px, 9 L2-resident
//      loads, 4x4 constant-weight bilinear in folded domain, 16x
//      sigmoid=rcp(1+2^z), 4 float4 stores. Barrier-free -> streams at the
//      ~15us store floor (R6 decomposition: standalone upsample ~= 15us,
//      vs ~20us when phase-locked inside the fused kernel, R13=30.9).
// Shapes fixed by harness: N=2, Cin=8, H=100, W=152, n_inst=100, stride=8.

#define CIN 8
#define HH 100
#define WW 152
#define HWSZ (HH * WW)
#define NI 100
#define OH (HH * 4)
#define OW (WW * 4)
#define NLOG2E (-1.44269504f)

__device__ __forceinline__ float fast_rcp(float x) {
    return __builtin_amdgcn_rcpf(x);       // v_rcp_f32, ~1 ulp
}

__device__ __forceinline__ float fast_mish(float x) {
    // mish(x) = x*n/(n+2), n=e(e+2), e=exp(x); clamp only exp arg (x>20 ->
    // factor==1 in fp32) -> branchless, exact. (R13-proven)
    float e = __expf(fminf(x, 20.f));
    float n = e * (e + 2.f);
    return x * n * fast_rcp(n + 2.f);
}

// folded sigmoid: z = -log2e*logit -> sigma = 1/(1+2^z)  (R15-proven)
__device__ __forceinline__ float fold_sigmoid(float z) {
    return fast_rcp(1.f + exp2f(z));
}

// ---- K1: quad MLP -> folded logits in d_ws. No halo, no LDS, no barrier. ----
__global__ void __launch_bounds__(256)
mlp_kernel(const float* __restrict__ mask_feats,
           const float* __restrict__ params,
           const float* __restrict__ inst_locs,
           const int* __restrict__ im_inds,
           const int* __restrict__ fpn_levels,
           const int* __restrict__ stride_ptr,
           float* __restrict__ logits) {
    const int inst = blockIdx.y;
    const int q = blockIdx.x * blockDim.x + threadIdx.x;   // quad index
    if (q >= HWSZ / 4) return;
    const int p4 = q * 4;
    const int py = p4 / WW;
    const int px = p4 - py * WW;

    // block-uniform weight pointer -> s_load/SGPR operands (R13-proven)
    const float* __restrict__ P = params + inst * 169;

    const int stride = stride_ptr[0];
    const float half = (float)(stride / 2);
    const float soi_tab[5] = {64.f, 128.f, 256.f, 512.f, 1024.f};
    const float inv_soi = 1.f / soi_tab[fpn_levels[inst]];
    const float lx = inst_locs[inst * 2 + 0];
    const float ly = inst_locs[inst * 2 + 1];
    const float dx = -(float)stride * inv_soi;

    const float relY = (ly - (float)(py * stride) - half) * inv_soi;
    const float x0b  = (lx - (float)(px * stride) - half) * inv_soi;

    const float* fb = mask_feats + (size_t)im_inds[inst] * CIN * HWSZ + p4;
    float4 f[CIN];
#pragma unroll
    for (int c = 0; c < CIN; ++c)
        f[c] = *reinterpret_cast<const float4*>(fb + (size_t)c * HWSZ);
#define FEAT(c, j) ((&f[c].x)[(j)])

    // layer 1: 10 -> 8, mish (w1[o][i]=P[o*10+i], b1=P[152+o])
    float h1[8][4];
#pragma unroll
    for (int o = 0; o < 8; ++o) {
        const float w0 = P[o * 10 + 0];
        const float rowterm = fmaf(P[o * 10 + 1], relY, P[152 + o]);
#pragma unroll
        for (int j = 0; j < 4; ++j) {
            float acc = fmaf(w0, x0b + (float)j * dx, rowterm);
#pragma unroll
            for (int c = 0; c < CIN; ++c) acc = fmaf(P[o * 10 + 2 + c], FEAT(c, j), acc);
            h1[o][j] = fast_mish(acc);
        }
    }
    // layers 2+3 fused, sigmoid-fold: L'[j] = -log2e*(b3 + sum w3[o]*mish(.))
    const float b3f = NLOG2E * P[168];
    float lo[4] = {b3f, b3f, b3f, b3f};
#pragma unroll
    for (int o = 0; o < 8; ++o) {
        const float b2 = P[160 + o];
        const float w3f = NLOG2E * P[144 + o];
#pragma unroll
        for (int j = 0; j < 4; ++j) {
            float acc = b2;
#pragma unroll
            for (int i = 0; i < 8; ++i) acc = fmaf(P[80 + o * 8 + i], h1[i][j], acc);
            lo[j] = fmaf(w3f, fast_mish(acc), lo[j]);
        }
    }
    *reinterpret_cast<float4*>(logits + (size_t)inst * HWSZ + p4) =
        make_float4(lo[0], lo[1], lo[2], lo[3]);
#undef FEAT
}

// ---- K2: streaming upsample+sigmoid. One thread per input px -> 4x4 out. ----
// Output row Y=4r+k weights (coord max(Y-2,0)/4, clamped; R2-verified):
//   k=0: .5 prev + .5 cur | k=1: .25 prev + .75 cur | k=2: cur | k=3: .75 cur + .25 next
__global__ void __launch_bounds__(256)
upsample_sigmoid_kernel(const float* __restrict__ logits,
                        float* __restrict__ out) {
    const int per_inst = HH * WW;
    const int idx = blockIdx.x * blockDim.x + threadIdx.x;
    if (idx >= NI * per_inst) return;

    const int inst = idx / per_inst;
    int rem = idx - inst * per_inst;
    const int r = rem / WW;
    const int g = rem - r * WW;

    const float* L = logits + (size_t)inst * HWSZ;
    const int rm1 = max(r - 1, 0), rp1 = min(r + 1, HH - 1);
    const int gm1 = max(g - 1, 0), gp1 = min(g + 1, WW - 1);

    const float v00 = L[rm1 * WW + gm1], v01 = L[rm1 * WW + g], v02 = L[rm1 * WW + gp1];
    const float v10 = L[r   * WW + gm1], v11 = L[r   * WW + g], v12 = L[r   * WW + gp1];
    const float v20 = L[rp1 * WW + gm1], v21 = L[rp1 * WW + g], v22 = L[rp1 * WW + gp1];

    float h0[4], h1[4], h2[4];
    h0[0] = 0.5f * (v00 + v01); h0[1] = fmaf(0.25f, v00, 0.75f * v01); h0[2] = v01; h0[3] = fmaf(0.25f, v02, 0.75f * v01);
    h1[0] = 0.5f * (v10 + v11); h1[1] = fmaf(0.25f, v10, 0.75f * v11); h1[2] = v11; h1[3] = fmaf(0.25f, v12, 0.75f * v11);
    h2[0] = 0.5f * (v20 + v21); h2[1] = fmaf(0.25f, v20, 0.75f * v21); h2[2] = v21; h2[3] = fmaf(0.25f, v22, 0.75f * v21);

    float* O = out + (size_t)inst * (OH * OW) + (size_t)(4 * r) * OW + 4 * g;
    float4 row;
    row.x = fold_sigmoid(0.5f * (h0[0] + h1[0]));
    row.y = fold_sigmoid(0.5f * (h0[1] + h1[1]));
    row.z = fold_sigmoid(0.5f * (h0[2] + h1[2]));
    row.w = fold_sigmoid(0.5f * (h0[3] + h1[3]));
    *reinterpret_cast<float4*>(O) = row;
    row.x = fold_sigmoid(fmaf(0.25f, h0[0], 0.75f * h1[0]));
    row.y = fold_sigmoid(fmaf(0.25f, h0[1], 0.75f * h1[1]));
    row.z = fold_sigmoid(fmaf(0.25f, h0[2], 0.75f * h1[2]));
    row.w = fold_sigmoid(fmaf(0.25f, h0[3], 0.75f * h1[3]));
    *reinterpret_cast<float4*>(O + OW) = row;
    row.x = fold_sigmoid(h1[0]);
    row.y = fold_sigmoid(h1[1]);
    row.z = fold_sigmoid(h1[2]);
    row.w = fold_sigmoid(h1[3]);
    *reinterpret_cast<float4*>(O + 2 * OW) = row;
    row.x = fold_sigmoid(fmaf(0.25f, h2[0], 0.75f * h1[0]));
    row.y = fold_sigmoid(fmaf(0.25f, h2[1], 0.75f * h1[1]));
    row.z = fold_sigmoid(fmaf(0.25f, h2[2], 0.75f * h1[2]));
    row.w = fold_sigmoid(fmaf(0.25f, h2[3], 0.75f * h1[3]));
    *reinterpret_cast<float4*>(O + 3 * OW) = row;
}

extern "C" void kernel_launch(void* const* d_in, const int* in_sizes, int n_in,
                              void* d_out, int out_size, void* d_ws, size_t ws_size,
                              hipStream_t stream) {
    const float* mask_feats = (const float*)d_in[0];
    const float* params     = (const float*)d_in[1];
    const float* inst_locs  = (const float*)d_in[2];
    const int*   im_inds    = (const int*)d_in[3];
    const int*   fpn_levels = (const int*)d_in[4];
    const int*   stride_ptr = (const int*)d_in[5];
    float* out    = (float*)d_out;
    float* logits = (float*)d_ws;            // NI*HWSZ floats = 6.08 MB (folded)

    dim3 block(256);
    const int quads = HWSZ / 4;              // 3800 per instance
    dim3 grid1((quads + 255) / 256, NI);     // 15 x 100
    mlp_kernel<<<grid1, block, 0, stream>>>(
        mask_feats, params, inst_locs, im_inds, fpn_levels, stride_ptr, logits);

    const int total_t = NI * HH * WW;        // 1,520,000
    dim3 grid2((total_t + 255) / 256);
    upsample_sigmoid_kernel<<<grid2, block, 0, stream>>>(logits, out);
}